// Round 11
// baseline (528.740 us; speedup 1.0000x reference)
//
#include <hip/hip_runtime.h>
#include <hip/hip_bf16.h>
#include <stdint.h>
#include <math.h>

#define NN 16384
#define DD 256
#define MARGIN_F 0.2f

typedef __attribute__((ext_vector_type(8))) short bf16x8;
typedef __attribute__((ext_vector_type(4))) float f32x4;

__device__ inline short f2bf(float f) {
    __hip_bfloat16 h = __float2bfloat16(f);
    return *reinterpret_cast<short*>(&h);
}

// monotone order-preserving float<->uint key (max via unsigned atomicMax)
__device__ inline unsigned fkey(float f) {
    unsigned b = __float_as_uint(f);
    return (b & 0x80000000u) ? ~b : (b | 0x80000000u);
}
__device__ inline float fdec(unsigned k) {
    return __uint_as_float((k & 0x80000000u) ? (k ^ 0x80000000u) : ~k);
}
#define NEG_INF_KEY 0x007FFFFFu   // fkey(-inf)

__device__ inline void gload16(const void* g, void* l) {
    __builtin_amdgcn_global_load_lds(
        (const __attribute__((address_space(1))) void*)g,
        (__attribute__((address_space(3))) void*)l, 16, 0, 0);
}

// ---------------- fused prep: f32->bf16 + diag + init maxes ----------------
__global__ __launch_bounds__(256) void fused_prep_kernel(
    const float* __restrict__ imgs, const float* __restrict__ caps,
    short* __restrict__ imgsb, short* __restrict__ capsb,
    float* __restrict__ diag, unsigned* __restrict__ rowmax,
    unsigned* __restrict__ colmax) {
    const int i = (blockIdx.x << 2) + (threadIdx.x >> 6);
    const int l = threadIdx.x & 63;
    const float4* a4 = reinterpret_cast<const float4*>(imgs + (size_t)i * DD);
    const float4* b4 = reinterpret_cast<const float4*>(caps + (size_t)i * DD);
    float4 av = a4[l];
    float4 bv = b4[l];
    short4 as, bs;
    as.x = f2bf(av.x); as.y = f2bf(av.y); as.z = f2bf(av.z); as.w = f2bf(av.w);
    bs.x = f2bf(bv.x); bs.y = f2bf(bv.y); bs.z = f2bf(bv.z); bs.w = f2bf(bv.w);
    reinterpret_cast<short4*>(imgsb + (size_t)i * DD)[l] = as;
    reinterpret_cast<short4*>(capsb + (size_t)i * DD)[l] = bs;
    float s = av.x * bv.x + av.y * bv.y + av.z * bv.z + av.w * bv.w;
    #pragma unroll
    for (int off = 32; off > 0; off >>= 1) s += __shfl_down(s, off);
    if (l == 0) {
        diag[i] = s;
        rowmax[i] = NEG_INF_KEY;
        colmax[i] = NEG_INF_KEY;
    }
}

// ---------------- main: A-resident strip kernel, cross-chunk pipeline ------
// 512 blocks = 128 row-panels x 4 col-strips. A panel -> registers. B 64-col
// chunks double-buffered via gload_lds + XOR swizzle. NEW: B fragments are
// register-pipelined ACROSS half-chunk boundaries: MFMA ks0-3 uses frags read
// during the previous chunk; reads for ks4-7 issue under that MFMA burst;
// after mid-barrier, MFMA ks4-7 runs while next chunk's ks0-3 frags load.
// No MFMA ever waits on a fresh ds_read.
__global__ __launch_bounds__(256, 2) void score_max_kernel(
    const short* __restrict__ imgsb, const short* __restrict__ capsb,
    const float* __restrict__ diag,
    unsigned* __restrict__ rowmax, unsigned* __restrict__ colmax) {

    __shared__ char lds[81920];   // [0,64K): A then 2x32KB B bufs; [64K,80K): colmax keys
    unsigned* clds = reinterpret_cast<unsigned*>(lds + 65536);

    const int bid   = blockIdx.x;
    const int panel = bid >> 2;
    const int strip = bid & 3;
    const int brow  = panel << 7;
    const int scol  = strip << 12;

    const int t    = threadIdx.x;
    const int wid  = t >> 6;
    const int lane = t & 63;
    const int wr   = wid >> 1;    // 0..1: 64-row half
    const int wc   = wid & 1;     // 0..1: 32-col half of 64-col chunk
    const int rg   = lane >> 4;   // 0..3
    const int cl   = lane & 15;   // 0..15

    // ---- init colmax keys ----
    #pragma unroll
    for (int i = 0; i < 16; ++i) clds[t + (i << 8)] = NEG_INF_KEY;

    // ---- stage A panel (64KB), chunk-swizzled ----
    {
        const int cs = t & 31;
        const int r0 = t >> 5;
        const int co = ((cs ^ (r0 & 7)) << 3);
        const short* src = imgsb + (((size_t)(brow + r0)) << 8) + co;
        #pragma unroll
        for (int i = 0; i < 16; ++i)
            gload16(src + ((size_t)i << 11), lds + t * 16 + i * 4096);
    }
    __syncthreads();

    // ---- A fragments to registers: af[m][ks] ----
    bf16x8 af[4][8];
    #pragma unroll
    for (int m = 0; m < 4; ++m) {
        const int row = wr * 64 + m * 16 + cl;
        const char* rb = lds + row * 512;
        const int sw = row & 7;
        #pragma unroll
        for (int ks = 0; ks < 8; ++ks) {
            const int k8 = (ks << 2) + rg;
            af[m][ks] = *reinterpret_cast<const bf16x8*>(rb + ((k8 ^ sw) << 4));
        }
    }
    __syncthreads();   // done reading A before B overwrites

    // ---- B staging geometry ----
    const int br0 = t >> 5;
    const int bco = (((t & 31) ^ (br0 & 7)) << 3);

    #define STAGEB(bo, cb) {                                                   \
        const short* s_ = capsb + (((size_t)((cb) + br0)) << 8) + bco;         \
        _Pragma("unroll")                                                      \
        for (int i_ = 0; i_ < 8; ++i_)                                         \
            gload16(s_ + ((size_t)i_ << 11), lds + (bo) + t * 16 + i_ * 4096); \
    }

    float rmx[4][4];
    #pragma unroll
    for (int m = 0; m < 4; ++m)
        #pragma unroll
        for (int r = 0; r < 4; ++r) rmx[m][r] = -INFINITY;

    // ---- swizzled B-read byte offsets (n=1 row is +16 -> same swizzle,
    //      so boff1[k] = boff0[k] + 8192 folds into the ds_read immediate) --
    const int rr0 = wc * 32 + cl;
    unsigned boff0[8];
    #pragma unroll
    for (int ks = 0; ks < 8; ++ks) {
        const int k8 = (ks << 2) + rg;
        boff0[ks] = rr0 * 512 + ((k8 ^ (rr0 & 7)) << 4);
    }

    // fragment read: parity P (0 / 32768), k-slot K, n-half W (0/1)
    #define RD(P, K, W) (*reinterpret_cast<const bf16x8*>(                     \
        lds + (P) + (W) * 8192 + boff0[K]))

    const f32x4 zv = (f32x4){0.f, 0.f, 0.f, 0.f};
    bf16x8 pa0[4], pa1[4], pb0[4], pb1[4];

    // ---- prologue: stage chunk 0, then preload its ks0-3 fragments ----
    STAGEB(0, scol);
    asm volatile("s_waitcnt vmcnt(0)" ::: "memory");
    __syncthreads();
    #pragma unroll
    for (int k = 0; k < 4; ++k) { pa0[k] = RD(0, k, 0); pa1[k] = RD(0, k, 1); }

    f32x4 acc[4][2];

    #define CHUNK(H, COFF, NOFF) {                                             \
        const int cb = scol + ((H) << 6);                                      \
        if ((H) < 63) STAGEB(NOFF, cb + 64);                                   \
        /* issue ks4-7 reads from current buffer */                            \
        _Pragma("unroll")                                                      \
        for (int k = 0; k < 4; ++k) {                                          \
            pb0[k] = RD(COFF, k + 4, 0);                                       \
            pb1[k] = RD(COFF, k + 4, 1);                                       \
        }                                                                      \
        __builtin_amdgcn_sched_barrier(0);                                     \
        /* MFMA ks0-3 on prefetched pa */                                      \
        __builtin_amdgcn_s_setprio(1);                                         \
        _Pragma("unroll")                                                      \
        for (int m = 0; m < 4; ++m) {                                          \
            acc[m][0] = __builtin_amdgcn_mfma_f32_16x16x32_bf16(               \
                af[m][0], pa0[0], zv, 0, 0, 0);                                \
            acc[m][1] = __builtin_amdgcn_mfma_f32_16x16x32_bf16(               \
                af[m][0], pa1[0], zv, 0, 0, 0);                                \
        }                                                                      \
        _Pragma("unroll")                                                      \
        for (int ks = 1; ks < 4; ++ks)                                         \
            _Pragma("unroll")                                                  \
            for (int m = 0; m < 4; ++m) {                                      \
                acc[m][0] = __builtin_amdgcn_mfma_f32_16x16x32_bf16(           \
                    af[m][ks], pa0[ks], acc[m][0], 0, 0, 0);                   \
                acc[m][1] = __builtin_amdgcn_mfma_f32_16x16x32_bf16(           \
                    af[m][ks], pa1[ks], acc[m][1], 0, 0, 0);                   \
            }                                                                  \
        __builtin_amdgcn_s_setprio(0);                                         \
        /* stage(H+1) has had the whole first half to land */                  \
        if ((H) < 63) asm volatile("s_waitcnt vmcnt(0)" ::: "memory");         \
        __builtin_amdgcn_s_barrier();                                          \
        asm volatile("" ::: "memory");                                        \
        /* preload next chunk's ks0-3 from the just-staged buffer */           \
        if ((H) < 63) {                                                        \
            _Pragma("unroll")                                                  \
            for (int k = 0; k < 4; ++k) {                                      \
                pa0[k] = RD(NOFF, k, 0);                                       \
                pa1[k] = RD(NOFF, k, 1);                                       \
            }                                                                  \
        }                                                                      \
        __builtin_amdgcn_sched_barrier(0);                                     \
        /* MFMA ks4-7 on pb (read a half-chunk ago) */                         \
        __builtin_amdgcn_s_setprio(1);                                         \
        _Pragma("unroll")                                                      \
        for (int ks = 0; ks < 4; ++ks)                                         \
            _Pragma("unroll")                                                  \
            for (int m = 0; m < 4; ++m) {                                      \
                acc[m][0] = __builtin_amdgcn_mfma_f32_16x16x32_bf16(           \
                    af[m][ks + 4], pb0[ks], acc[m][0], 0, 0, 0);               \
                acc[m][1] = __builtin_amdgcn_mfma_f32_16x16x32_bf16(           \
                    af[m][ks + 4], pb1[ks], acc[m][1], 0, 0, 0);               \
            }                                                                  \
        __builtin_amdgcn_s_setprio(0);                                         \
        /* epilogue: diag fix, row-max, col-max */                             \
        if (cb < brow + 128 && cb + 64 > brow) {                               \
            _Pragma("unroll")                                                  \
            for (int m = 0; m < 4; ++m)                                        \
                _Pragma("unroll")                                              \
                for (int r = 0; r < 4; ++r) {                                  \
                    const int i = brow + wr * 64 + m * 16 + (rg << 2) + r;     \
                    const int d = i - cb - wc * 32;                            \
                    _Pragma("unroll")                                          \
                    for (int n = 0; n < 2; ++n)                                \
                        if (d == n * 16 + cl) acc[m][n][r] = -diag[i];         \
                }                                                              \
        }                                                                      \
        _Pragma("unroll")                                                      \
        for (int m = 0; m < 4; ++m)                                            \
            _Pragma("unroll")                                                  \
            for (int r = 0; r < 4; ++r)                                        \
                rmx[m][r] = fmaxf(rmx[m][r],                                   \
                                  fmaxf(acc[m][0][r], acc[m][1][r]));          \
        _Pragma("unroll")                                                      \
        for (int n = 0; n < 2; ++n) {                                          \
            float v = acc[0][n][0];                                            \
            _Pragma("unroll")                                                  \
            for (int m = 0; m < 4; ++m)                                        \
                _Pragma("unroll")                                              \
                for (int r = 0; r < 4; ++r)                                    \
                    v = fmaxf(v, acc[m][n][r]);                                \
            v = fmaxf(v, __shfl_xor(v, 16));                                   \
            v = fmaxf(v, __shfl_xor(v, 32));                                   \
            if (rg == 0)                                                       \
                atomicMax(&clds[((H) << 6) + wc * 32 + n * 16 + cl], fkey(v)); \
        }                                                                      \
        __builtin_amdgcn_s_barrier();                                          \
        asm volatile("" ::: "memory");                                        \
    }

    for (int hh = 0; hh < 64; hh += 2) {
        CHUNK(hh, 0, 32768);
        CHUNK(hh + 1, 32768, 0);
    }
    #undef CHUNK
    #undef RD
    #undef STAGEB

    // ---- flush colmax keys to global ----
    __syncthreads();
    #pragma unroll
    for (int i = 0; i < 16; ++i) {
        const int c = t + (i << 8);
        atomicMax(&colmax[scol + c], clds[c]);
    }

    // ---- row-max writeout ----
    #pragma unroll
    for (int m = 0; m < 4; ++m)
        #pragma unroll
        for (int r = 0; r < 4; ++r) {
            float v = rmx[m][r];
            v = fmaxf(v, __shfl_xor(v, 1));
            v = fmaxf(v, __shfl_xor(v, 2));
            v = fmaxf(v, __shfl_xor(v, 4));
            v = fmaxf(v, __shfl_xor(v, 8));
            if (cl == 0)
                atomicMax(&rowmax[brow + wr * 64 + m * 16 + (rg << 2) + r],
                          fkey(v));
        }
}

// ---------------- finalize: hinge + total sum ----------------
__global__ __launch_bounds__(1024) void finalize_kernel(
    const float* __restrict__ diag,
    const unsigned* __restrict__ rowmax,
    const unsigned* __restrict__ colmax,
    float* __restrict__ out) {
    __shared__ float red[1024];
    int t = threadIdx.x;
    float s = 0.f;
    for (int idx = t; idx < 2 * NN; idx += 1024) {
        int i = idx & (NN - 1);
        float mx = fdec((idx < NN) ? colmax[i] : rowmax[i]);
        s += fmaxf(mx + (MARGIN_F - diag[i]), 0.f);
    }
    red[t] = s;
    __syncthreads();
    for (int off = 512; off > 0; off >>= 1) {
        if (t < off) red[t] += red[t + off];
        __syncthreads();
    }
    if (t == 0) out[0] = red[0];
}

extern "C" void kernel_launch(void* const* d_in, const int* in_sizes, int n_in,
                              void* d_out, int out_size, void* d_ws, size_t ws_size,
                              hipStream_t stream) {
    const float* imgs = reinterpret_cast<const float*>(d_in[0]);
    const float* caps = reinterpret_cast<const float*>(d_in[1]);

    float* diag      = reinterpret_cast<float*>(d_ws);
    unsigned* rowmax = reinterpret_cast<unsigned*>(diag + NN);
    unsigned* colmax = rowmax + NN;
    short* imgsb     = reinterpret_cast<short*>(colmax + NN);
    short* capsb     = imgsb + (size_t)NN * DD;

    fused_prep_kernel<<<NN / 4, 256, 0, stream>>>(imgs, caps, imgsb, capsb,
                                                  diag, rowmax, colmax);

    score_max_kernel<<<512, 256, 0, stream>>>(imgsb, capsb, diag,
                                              rowmax, colmax);

    finalize_kernel<<<1, 1024, 0, stream>>>(diag, rowmax, colmax,
                                            reinterpret_cast<float*>(d_out));
}

// Round 12
// 110.015 us; speedup vs baseline: 4.8061x; 4.8061x over previous
//
#include <hip/hip_runtime.h>
#include <hip/hip_bf16.h>
#include <hip/hip_fp8.h>
#include <stdint.h>
#include <math.h>

#define NN 16384
#define DD 256
#define MARGIN_F 0.2f

typedef __attribute__((ext_vector_type(8))) int int32x8;
typedef __attribute__((ext_vector_type(4))) float f32x4;

// monotone order-preserving float<->uint key (max via unsigned atomicMax)
__device__ inline unsigned fkey(float f) {
    unsigned b = __float_as_uint(f);
    return (b & 0x80000000u) ? ~b : (b | 0x80000000u);
}
__device__ inline float fdec(unsigned k) {
    return __uint_as_float((k & 0x80000000u) ? (k ^ 0x80000000u) : ~k);
}
#define NEG_INF_KEY 0x007FFFFFu   // fkey(-inf)

__device__ inline void gload16(const void* g, void* l) {
    __builtin_amdgcn_global_load_lds(
        (const __attribute__((address_space(1))) void*)g,
        (__attribute__((address_space(3))) void*)l, 16, 0, 0);
}

__device__ inline unsigned pk8(float4 v) {
    __hip_fp8_e4m3 q0(v.x), q1(v.y), q2(v.z), q3(v.w);
    return (unsigned)q0.__x | ((unsigned)q1.__x << 8) |
           ((unsigned)q2.__x << 16) | ((unsigned)q3.__x << 24);
}

// ---------------- fused prep: f32->fp8 e4m3 + diag + init maxes ------------
__global__ __launch_bounds__(256) void fused_prep_kernel(
    const float* __restrict__ imgs, const float* __restrict__ caps,
    unsigned char* __restrict__ imgs8, unsigned char* __restrict__ caps8,
    float* __restrict__ diag, unsigned* __restrict__ rowmax,
    unsigned* __restrict__ colmax) {
    const int i = (blockIdx.x << 2) + (threadIdx.x >> 6);
    const int l = threadIdx.x & 63;
    const float4* a4 = reinterpret_cast<const float4*>(imgs + (size_t)i * DD);
    const float4* b4 = reinterpret_cast<const float4*>(caps + (size_t)i * DD);
    float4 av = a4[l];
    float4 bv = b4[l];
    reinterpret_cast<unsigned*>(imgs8 + (size_t)i * DD)[l] = pk8(av);
    reinterpret_cast<unsigned*>(caps8 + (size_t)i * DD)[l] = pk8(bv);
    float s = av.x * bv.x + av.y * bv.y + av.z * bv.z + av.w * bv.w;
    #pragma unroll
    for (int off = 32; off > 0; off >>= 1) s += __shfl_down(s, off);
    if (l == 0) {
        diag[i] = s;
        rowmax[i] = NEG_INF_KEY;
        colmax[i] = NEG_INF_KEY;
    }
}

// ---------------- main: A-resident strip kernel, MX-fp8 K=128 MFMA ---------
// R7 sync skeleton (proven): 512 blocks = 128 row-panels x 4 col-strips.
// A panel (128x256 fp8 = 32KB) staged once via gload_lds -> af[4][2] int32x8
// (64 VGPRs). B 64-col chunks (16KB fp8) double-buffered via gload_lds with
// 32B-pair XOR swizzle; counted vmcnt(4) pipeline. mfma_scale 16x16x128 with
// unit scales (E8M0 byte 127) = pure fp8 GEMM at 2x bf16 rate, 4x K per inst.
__global__ __launch_bounds__(256, 2) void score_max_kernel(
    const unsigned char* __restrict__ imgs8,
    const unsigned char* __restrict__ caps8,
    const float* __restrict__ diag,
    unsigned* __restrict__ rowmax, unsigned* __restrict__ colmax) {

    __shared__ char lds[49152];   // [0,32K): A then 2x16KB B bufs; [32K,48K): colmax keys
    unsigned* clds = reinterpret_cast<unsigned*>(lds + 32768);

    const int bid   = blockIdx.x;
    const int panel = bid >> 2;
    const int strip = bid & 3;
    const int brow  = panel << 7;
    const int scol  = strip << 12;

    const int t    = threadIdx.x;
    const int wid  = t >> 6;
    const int lane = t & 63;
    const int wr   = wid >> 1;    // 0..1: 64-row half
    const int wc   = wid & 1;     // 0..1: 32-col half of 64-col chunk
    const int rg   = lane >> 4;   // 0..3
    const int cl   = lane & 15;   // 0..15

    // ---- init colmax keys (4096 u32) ----
    #pragma unroll
    for (int i = 0; i < 16; ++i) clds[t + (i << 8)] = NEG_INF_KEY;

    // ---- staging geometry: dest granule d = t + 256*i; row = (t>>4)+16i,
    //      slot = t&15 (invariant). 32B-pair swizzle: pair' = pair ^ (row&7).
    const int sl = t & 15;
    const int rw = t >> 4;
    const int srcoff = (((sl >> 1) ^ (rw & 7)) << 5) + ((sl & 1) << 4);

    // ---- stage A panel (32KB fp8) ----
    {
        const unsigned char* src = imgs8 + (((size_t)(brow + rw)) << 8) + srcoff;
        #pragma unroll
        for (int i = 0; i < 8; ++i)
            gload16(src + ((size_t)i << 12), lds + t * 16 + i * 4096);
    }
    __syncthreads();

    // ---- A fragments: af[m][ks], row = wr*64+m*16+cl, k = rg*32 (+ks*128) --
    int32x8 af[4][2];
    #pragma unroll
    for (int m = 0; m < 4; ++m) {
        const int row = wr * 64 + m * 16 + cl;
        #pragma unroll
        for (int ks = 0; ks < 2; ++ks)
            af[m][ks] = *reinterpret_cast<const int32x8*>(
                lds + row * 256 + (((rg + (ks << 2)) ^ (cl & 7)) << 5));
    }
    __syncthreads();   // done reading A before B overwrites

    #define STAGEB(bo, cb) {                                                   \
        const unsigned char* s_ =                                              \
            caps8 + (((size_t)((cb) + rw)) << 8) + srcoff;                     \
        _Pragma("unroll")                                                      \
        for (int i_ = 0; i_ < 4; ++i_)                                         \
            gload16(s_ + ((size_t)i_ << 12), lds + (bo) + t * 16 + i_ * 4096); \
    }

    // prologue: issue stage(0) into buf0 (completion enforced at h=0 top)
    STAGEB(0, scol);

    float rmx[4][4];
    #pragma unroll
    for (int m = 0; m < 4; ++m)
        #pragma unroll
        for (int r = 0; r < 4; ++r) rmx[m][r] = -INFINITY;

    // ---- B-read byte offsets (n=1 row = +16 rows -> +4096, same swizzle) --
    const int rr0 = wc * 32 + cl;
    unsigned boff[2];
    #pragma unroll
    for (int ks = 0; ks < 2; ++ks)
        boff[ks] = rr0 * 256 + (((rg + (ks << 2)) ^ (cl & 7)) << 5);

    const f32x4 zv = (f32x4){0.f, 0.f, 0.f, 0.f};
    #define SCL 0x7F7F7F7F   // E8M0 exponent 127 = 1.0 in every byte

    for (int h = 0; h < 64; ++h) {
        const int cb = scol + (h << 6);
        const char* cur = lds + ((h & 1) << 14);

        // barrier 1: all waves done reading buf[(h+1)&1] (chunk h-1)
        __builtin_amdgcn_s_barrier();
        asm volatile("" ::: "memory");
        if (h < 63) {
            STAGEB(((h + 1) & 1) << 14, cb + 64);
            // oldest-beyond-4 = stage(h): wait it; stage(h+1) stays in flight
            asm volatile("s_waitcnt vmcnt(4)" ::: "memory");
        } else {
            asm volatile("s_waitcnt vmcnt(0)" ::: "memory");
        }
        // barrier 2: stage(h) visible to all waves
        __builtin_amdgcn_s_barrier();
        asm volatile("" ::: "memory");

        // ---- B fragments (4 x 32B LDS reads) ----
        int32x8 b00 = *reinterpret_cast<const int32x8*>(cur + boff[0]);
        int32x8 b01 = *reinterpret_cast<const int32x8*>(cur + boff[0] + 4096);
        int32x8 b10 = *reinterpret_cast<const int32x8*>(cur + boff[1]);
        int32x8 b11 = *reinterpret_cast<const int32x8*>(cur + boff[1] + 4096);

        f32x4 acc[4][2];
        __builtin_amdgcn_s_setprio(1);
        #pragma unroll
        for (int m = 0; m < 4; ++m) {
            acc[m][0] = __builtin_amdgcn_mfma_scale_f32_16x16x128_f8f6f4(
                af[m][0], b00, zv, 0, 0, 0, SCL, 0, SCL);
            acc[m][1] = __builtin_amdgcn_mfma_scale_f32_16x16x128_f8f6f4(
                af[m][0], b01, zv, 0, 0, 0, SCL, 0, SCL);
        }
        #pragma unroll
        for (int m = 0; m < 4; ++m) {
            acc[m][0] = __builtin_amdgcn_mfma_scale_f32_16x16x128_f8f6f4(
                af[m][1], b10, acc[m][0], 0, 0, 0, SCL, 0, SCL);
            acc[m][1] = __builtin_amdgcn_mfma_scale_f32_16x16x128_f8f6f4(
                af[m][1], b11, acc[m][1], 0, 0, 0, SCL, 0, SCL);
        }
        __builtin_amdgcn_s_setprio(0);

        // ---- diagonal fix (at most 2 chunks per block): exact f32 ----
        if (cb < brow + 128 && cb + 64 > brow) {
            #pragma unroll
            for (int m = 0; m < 4; ++m)
                #pragma unroll
                for (int r = 0; r < 4; ++r) {
                    const int i = brow + wr * 64 + m * 16 + (rg << 2) + r;
                    const int d = i - cb - wc * 32;
                    #pragma unroll
                    for (int n = 0; n < 2; ++n)
                        if (d == n * 16 + cl) acc[m][n][r] = -diag[i];
                }
        }

        // ---- running row-max (pure register) ----
        #pragma unroll
        for (int m = 0; m < 4; ++m)
            #pragma unroll
            for (int r = 0; r < 4; ++r)
                rmx[m][r] = fmaxf(rmx[m][r],
                                  fmaxf(acc[m][0][r], acc[m][1][r]));

        // ---- col-max -> clds keys ----
        #pragma unroll
        for (int n = 0; n < 2; ++n) {
            float v = acc[0][n][0];
            #pragma unroll
            for (int m = 0; m < 4; ++m)
                #pragma unroll
                for (int r = 0; r < 4; ++r)
                    v = fmaxf(v, acc[m][n][r]);
            v = fmaxf(v, __shfl_xor(v, 16));
            v = fmaxf(v, __shfl_xor(v, 32));
            if (rg == 0)
                atomicMax(&clds[(h << 6) + wc * 32 + n * 16 + cl], fkey(v));
        }
    }

    // ---- flush colmax keys to global ----
    __syncthreads();
    #pragma unroll
    for (int i = 0; i < 16; ++i) {
        const int c = t + (i << 8);
        atomicMax(&colmax[scol + c], clds[c]);
    }

    // ---- row-max writeout ----
    #pragma unroll
    for (int m = 0; m < 4; ++m)
        #pragma unroll
        for (int r = 0; r < 4; ++r) {
            float v = rmx[m][r];
            v = fmaxf(v, __shfl_xor(v, 1));
            v = fmaxf(v, __shfl_xor(v, 2));
            v = fmaxf(v, __shfl_xor(v, 4));
            v = fmaxf(v, __shfl_xor(v, 8));
            if (cl == 0)
                atomicMax(&rowmax[brow + wr * 64 + m * 16 + (rg << 2) + r],
                          fkey(v));
        }
    #undef STAGEB
}

// ---------------- finalize: hinge + total sum ----------------
__global__ __launch_bounds__(1024) void finalize_kernel(
    const float* __restrict__ diag,
    const unsigned* __restrict__ rowmax,
    const unsigned* __restrict__ colmax,
    float* __restrict__ out) {
    __shared__ float red[1024];
    int t = threadIdx.x;
    float s = 0.f;
    for (int idx = t; idx < 2 * NN; idx += 1024) {
        int i = idx & (NN - 1);
        float mx = fdec((idx < NN) ? colmax[i] : rowmax[i]);
        s += fmaxf(mx + (MARGIN_F - diag[i]), 0.f);
    }
    red[t] = s;
    __syncthreads();
    for (int off = 512; off > 0; off >>= 1) {
        if (t < off) red[t] += red[t + off];
        __syncthreads();
    }
    if (t == 0) out[0] = red[0];
}

extern "C" void kernel_launch(void* const* d_in, const int* in_sizes, int n_in,
                              void* d_out, int out_size, void* d_ws, size_t ws_size,
                              hipStream_t stream) {
    const float* imgs = reinterpret_cast<const float*>(d_in[0]);
    const float* caps = reinterpret_cast<const float*>(d_in[1]);

    float* diag          = reinterpret_cast<float*>(d_ws);
    unsigned* rowmax     = reinterpret_cast<unsigned*>(diag + NN);
    unsigned* colmax     = rowmax + NN;
    unsigned char* imgs8 = reinterpret_cast<unsigned char*>(colmax + NN);
    unsigned char* caps8 = imgs8 + (size_t)NN * DD;

    fused_prep_kernel<<<NN / 4, 256, 0, stream>>>(imgs, caps, imgs8, caps8,
                                                  diag, rowmax, colmax);

    score_max_kernel<<<512, 256, 0, stream>>>(imgs8, caps8, diag,
                                              rowmax, colmax);

    finalize_kernel<<<1, 1024, 0, stream>>>(diag, rowmax, colmax,
                                            reinterpret_cast<float*>(d_out));
}